// Round 9
// baseline (521.801 us; speedup 1.0000x reference)
//
#include <hip/hip_runtime.h>

// SoftSymmetricAlignment: B=4, N=M=512, D=128, fp32.
// z[b,n,m] = sum_d |x[b,n,d]-y[b,m,d]|; alpha=softmax_n(-z), beta=softmax_m(-z)
// over the valid region only (masked -1e9 entries underflow to exactly 0);
// a = alpha+beta-alpha*beta; out[b] = -sum(a*z)/sum(a).
//
// R9: bounded software pipeline. R8's 8-wide ping-pong spilled (VGPR 256 +
// 171MB scratch writes). Now: 4-wide chunks, two alternating buffer sets with
// the dd-loop unrolled by 2 (12 float4 = 48 buffer regs, no copies), and
// __launch_bounds__(256,3) caps VGPR ~168 (3 blocks/CU; LDS 51.5KB x3 fits).
// Also: k2's 1024 same-address atomics -> 32 slots per (b, num/den) to kill
// same-dword RMW serialization; k3 sums slots in one wave.
// No device-scope fences (R3/R4/R6: 20-40us each on 8-XCD gfx950).

constexpr int B = 4, N = 512, M = 512, D = 128;
constexpr int TN = 64, TM = 32;
constexpr int LSTR = D + 4;           // +4 floats pad: rows step 4 banks
constexpr int NSLOT = 32;             // accumulator slots per quantity
#define SENT -3.0e38f                  // "minus infinity" that is exp-safe (no inf-inf NaN)

// lengths: jnp.int64 in the reference, but JAX w/o x64 gives int32. Lengths are
// >=64, so odd int32 slots are 0 iff the buffer is int64 little-endian.
__device__ __forceinline__ int load_len(const int* p, int b) {
  bool is64 = (p[1] == 0) && (p[3] == 0);
  return is64 ? p[2 * b] : p[b];
}

// Stage x(64x128) + y(32x128) tiles into LDS; compute zr[2][4] for
// n = n0 + ty + 32i, m = m0 + tx + 8j  (tx = tid&7, ty = tid>>3).
// Inner loop: 4-float chunks, 2 alternating register sets (1-deep prefetch).
__device__ __forceinline__ void compute_tile(const float* __restrict__ x,
                                             const float* __restrict__ y,
                                             int b, int n0, int m0, int tid,
                                             float* xs, float* ys,
                                             float zr[2][4]) {
  const float4* xg = (const float4*)(x + (size_t)(b * N + n0) * D);
  const float4* yg = (const float4*)(y + (size_t)(b * M + m0) * D);
#pragma unroll
  for (int k = 0; k < 8; ++k) {        // 2048 float4 of x
    int idx = tid + k * 256;
    int r = idx >> 5;                  // 32 float4 per row
    int c = (idx & 31) << 2;
    *(float4*)&xs[r * LSTR + c] = xg[idx];
  }
#pragma unroll
  for (int k = 0; k < 4; ++k) {        // 1024 float4 of y
    int idx = tid + k * 256;
    int r = idx >> 5;
    int c = (idx & 31) << 2;
    *(float4*)&ys[r * LSTR + c] = yg[idx];
  }
  __syncthreads();

  const int tx = tid & 7;
  const int ty = tid >> 3;
  const float* xr0 = &xs[ty * LSTR];
  const float* xr1 = &xs[(ty + 32) * LSTR];
  const float* yr0 = &ys[(tx     ) * LSTR];
  const float* yr1 = &ys[(tx +  8) * LSTR];
  const float* yr2 = &ys[(tx + 16) * LSTR];
  const float* yr3 = &ys[(tx + 24) * LSTR];

#pragma unroll
  for (int i = 0; i < 2; ++i)
#pragma unroll
    for (int j = 0; j < 4; ++j) zr[i][j] = 0.f;

  float4 xa[2], yb[4], xc[2], yd[4];   // two buffer sets, 12 float4 total

#define LOAD_SET(XA, YB, dd)                \
  do {                                      \
    XA[0] = *(const float4*)&xr0[(dd)];     \
    XA[1] = *(const float4*)&xr1[(dd)];     \
    YB[0] = *(const float4*)&yr0[(dd)];     \
    YB[1] = *(const float4*)&yr1[(dd)];     \
    YB[2] = *(const float4*)&yr2[(dd)];     \
    YB[3] = *(const float4*)&yr3[(dd)];     \
  } while (0)
#define COMPUTE_SET(XA, YB)                         \
  do {                                              \
    _Pragma("unroll")                               \
    for (int i = 0; i < 2; ++i)                     \
      _Pragma("unroll")                             \
      for (int j = 0; j < 4; ++j) {                 \
        zr[i][j] += fabsf(XA[i].x - YB[j].x);       \
        zr[i][j] += fabsf(XA[i].y - YB[j].y);       \
        zr[i][j] += fabsf(XA[i].z - YB[j].z);       \
        zr[i][j] += fabsf(XA[i].w - YB[j].w);       \
      }                                             \
  } while (0)

  LOAD_SET(xa, yb, 0);
#pragma unroll
  for (int dd = 0; dd < D; dd += 8) {   // 16 iterations, no buffer copies
    LOAD_SET(xc, yd, dd + 4);
    COMPUTE_SET(xa, yb);
    if (dd + 8 < D) LOAD_SET(xa, yb, dd + 8);
    COMPUTE_SET(xc, yd);
  }
#undef LOAD_SET
#undef COMPUTE_SET
}

// k1: per-tile softmax partials.
//   rp[b][mt][n] = (max, sumexp) over this m-tile's valid m, for row n   (mt: 16)
//   cp[b][nt][m] = (max, sumexp) over this n-tile's valid n, for col m   (nt: 8)
__global__ __launch_bounds__(256, 3) void k1_stats(const float* __restrict__ x,
                                                   const float* __restrict__ y,
                                                   const int* __restrict__ xlen,
                                                   const int* __restrict__ ylen,
                                                   float2* __restrict__ rp,
                                                   float2* __restrict__ cp,
                                                   float* __restrict__ acc) {
  __shared__ float xs[TN * LSTR];
  __shared__ float ys[TM * LSTR];
  __shared__ float2 colp[4][TM];
  const int b  = blockIdx.z;
  const int n0 = blockIdx.y * TN;
  const int m0 = blockIdx.x * TM;
  const int tid = threadIdx.x;
  const int xl = load_len(xlen, b);
  const int yl = load_len(ylen, b);

  if (blockIdx.x == 0 && blockIdx.y == 0 && blockIdx.z == 0)
    acc[tid] = 0.f;                    // all 2*B*NSLOT = 256 slots

  float zr[2][4];
  compute_tile(x, y, b, n0, m0, tid, xs, ys, zr);

  const int tx = tid & 7;        // m group (lane bits 0..2)
  const int ty = tid >> 3;       // n group (lane bits 3..5 + wave id)
  const int wv = tid >> 6;

  // row partials: reduce the 8 tx lanes (lane bits 0..2); row fully in-wave
#pragma unroll
  for (int i = 0; i < 2; ++i) {
    float lm = SENT;
#pragma unroll
    for (int j = 0; j < 4; ++j)
      if (m0 + tx + 8 * j < yl) lm = fmaxf(lm, -zr[i][j]);
#pragma unroll
    for (int off = 1; off <= 4; off <<= 1) lm = fmaxf(lm, __shfl_xor(lm, off, 64));
    float ls = 0.f;
#pragma unroll
    for (int j = 0; j < 4; ++j)
      if (m0 + tx + 8 * j < yl) ls += __expf(-zr[i][j] - lm);
#pragma unroll
    for (int off = 1; off <= 4; off <<= 1) ls += __shfl_xor(ls, off, 64);
    if (tx == 0)
      rp[((b * 16 + (m0 >> 5)) * N) + n0 + ty + 32 * i] = make_float2(lm, ls);
  }

  // col partials: reduce ty bits 3..5 in-wave, then 4 waves via LDS
#pragma unroll
  for (int j = 0; j < 4; ++j) {
    float cm = SENT;
#pragma unroll
    for (int i = 0; i < 2; ++i)
      if (n0 + ty + 32 * i < xl) cm = fmaxf(cm, -zr[i][j]);
    cm = fmaxf(cm, __shfl_xor(cm, 8, 64));
    cm = fmaxf(cm, __shfl_xor(cm, 16, 64));
    cm = fmaxf(cm, __shfl_xor(cm, 32, 64));
    float cs = 0.f;
#pragma unroll
    for (int i = 0; i < 2; ++i)
      if (n0 + ty + 32 * i < xl) cs += __expf(-zr[i][j] - cm);
    cs += __shfl_xor(cs, 8, 64);
    cs += __shfl_xor(cs, 16, 64);
    cs += __shfl_xor(cs, 32, 64);
    if ((ty & 7) == 0) colp[wv][tx + 8 * j] = make_float2(cm, cs);
  }
  __syncthreads();
  if (tid < TM) {
    float2 p0 = colp[0][tid], p1 = colp[1][tid], p2 = colp[2][tid], p3 = colp[3][tid];
    float gm = fmaxf(fmaxf(p0.x, p1.x), fmaxf(p2.x, p3.x));
    float gs = p0.y * __expf(p0.x - gm) + p1.y * __expf(p1.x - gm) +
               p2.y * __expf(p2.x - gm) + p3.y * __expf(p3.x - gm);
    cp[((b * 8 + (n0 >> 6)) * M) + m0 + tid] = make_float2(gm, gs);
  }
}

// k2: recompute zr, merge this block's row/col stats, accumulate num/den into
// slotted accumulators (no fence, no counter, low atomic contention).
__global__ __launch_bounds__(256, 3) void k2_final(const float* __restrict__ x,
                                                   const float* __restrict__ y,
                                                   const int* __restrict__ xlen,
                                                   const int* __restrict__ ylen,
                                                   const float2* __restrict__ rp,
                                                   const float2* __restrict__ cp,
                                                   float* __restrict__ acc) {
  __shared__ float xs[TN * LSTR];
  __shared__ float ys[TM * LSTR];
  __shared__ float rm_s[TN], ri_s[TN], cm_s[TM], ci_s[TM];
  __shared__ float red[4][2];
  const int b  = blockIdx.z;
  const int n0 = blockIdx.y * TN;
  const int m0 = blockIdx.x * TM;
  const int tid = threadIdx.x;
  const int xl = load_len(xlen, b);
  const int yl = load_len(ylen, b);

  // merge partials: tid<64 -> row n0+tid (16 m-tile partials);
  // tid in [64,96) -> col m0+(tid-64) (8 n-tile partials).
  if (tid < 64) {
    int n = n0 + tid;
    float gm = SENT;
    float2 v[16];
#pragma unroll
    for (int t = 0; t < 16; ++t) {
      v[t] = rp[(b * 16 + t) * N + n];
      gm = fmaxf(gm, v[t].x);
    }
    float gs = 0.f;
#pragma unroll
    for (int t = 0; t < 16; ++t) gs += v[t].y * __expf(v[t].x - gm);
    rm_s[tid] = gm;
    ri_s[tid] = 1.0f / gs;        // inf only for fully-masked rows (never used)
  } else if (tid < 96) {
    int m = m0 + tid - 64;
    float gm = SENT;
    float2 v[8];
#pragma unroll
    for (int t = 0; t < 8; ++t) {
      v[t] = cp[(b * 8 + t) * M + m];
      gm = fmaxf(gm, v[t].x);
    }
    float gs = 0.f;
#pragma unroll
    for (int t = 0; t < 8; ++t) gs += v[t].y * __expf(v[t].x - gm);
    cm_s[tid - 64] = gm;
    ci_s[tid - 64] = 1.0f / gs;
  }
  // compute_tile's __syncthreads() publishes the stat merge too

  float zr[2][4];
  compute_tile(x, y, b, n0, m0, tid, xs, ys, zr);

  const int tx = tid & 7;
  const int ty = tid >> 3;
  float num = 0.f, den = 0.f;
#pragma unroll
  for (int i = 0; i < 2; ++i) {
    int nl = ty + 32 * i;
    if (n0 + nl >= xl) continue;
    float rm = rm_s[nl], ri = ri_s[nl];
#pragma unroll
    for (int j = 0; j < 4; ++j) {
      int ml = tx + 8 * j;
      if (m0 + ml >= yl) continue;
      float zv = zr[i][j];
      float w = -zv;
      float alpha = __expf(w - cm_s[ml]) * ci_s[ml];
      float beta  = __expf(w - rm) * ri;
      float a = alpha + beta - alpha * beta;
      num += a * zv;
      den += a;
    }
  }
#pragma unroll
  for (int off = 32; off > 0; off >>= 1) {
    num += __shfl_xor(num, off, 64);
    den += __shfl_xor(den, off, 64);
  }
  if ((tid & 63) == 0) { red[tid >> 6][0] = num; red[tid >> 6][1] = den; }
  __syncthreads();
  if (tid == 0) {
    int slot = (blockIdx.x + blockIdx.y) & (NSLOT - 1);
    atomicAdd(&acc[b * NSLOT + slot],
              red[0][0] + red[1][0] + red[2][0] + red[3][0]);
    atomicAdd(&acc[(B + b) * NSLOT + slot],
              red[0][1] + red[1][1] + red[2][1] + red[3][1]);
  }
}

// Single wave: threads 0..7 each sum 32 slots; lanes 0..3 combine via shfl.
__global__ void k3_out(const float* __restrict__ acc, float* __restrict__ out) {
  int t = threadIdx.x;
  float s = 0.f;
  if (t < 2 * B) {
#pragma unroll
    for (int k = 0; k < NSLOT; ++k) s += acc[t * NSLOT + k];
  }
  float nsum = __shfl(s, t, 64);           // lane t's own row sum
  float dsum = __shfl(s, t + B, 64);
  if (t < B) out[t] = -nsum / dsum;
}

extern "C" void kernel_launch(void* const* d_in, const int* in_sizes, int n_in,
                              void* d_out, int out_size, void* d_ws, size_t ws_size,
                              hipStream_t stream) {
  const float* x    = (const float*)d_in[0];
  const float* y    = (const float*)d_in[1];
  const int*   xlen = (const int*)d_in[2];
  const int*   ylen = (const int*)d_in[3];
  float* out = (float*)d_out;

  float* ws = (float*)d_ws;
  float2* rp  = (float2*)ws;              size_t off = (size_t)B * 16 * N * 2; // 256 KB
  float2* cp  = (float2*)(ws + off);      off += (size_t)B * 8 * M * 2;        // 128 KB
  float*  acc = ws + off;                 off += 2 * B * NSLOT;

  k1_stats<<<dim3(M / TM, N / TN, B), 256, 0, stream>>>(x, y, xlen, ylen, rp, cp, acc);
  k2_final<<<dim3(M / TM, N / TN, B), 256, 0, stream>>>(x, y, xlen, ylen, rp, cp, acc);
  k3_out<<<1, 64, 0, stream>>>(acc, out);
}

// Round 10
// 93.202 us; speedup vs baseline: 5.5986x; 5.5986x over previous
//
#include <hip/hip_runtime.h>

// SoftSymmetricAlignment: B=4, N=M=512, D=128, fp32.
// z[b,n,m] = sum_d |x[b,n,d]-y[b,m,d]|; alpha=softmax_n(-z), beta=softmax_m(-z)
// over the valid region only (masked -1e9 entries underflow to exactly 0);
// a = alpha+beta-alpha*beta; out[b] = -sum(a*z)/sum(a).
//
// R10: revert to the measured-best R5 structure (96.3us): TN=TM=64 tiles,
// flash-style recompute (no z tensor), 3 stream-ordered kernels, NO fences
// (R3/R4/R6: device-scope fence/grid.sync = 20-40us on 8-XCD gfx950), NO
// hand pipelining and NO launch_bounds min-waves clause (R8: VGPR 256 spill;
// R9: launch_bounds(256,3) -> VGPR 84 spill, 600MB scratch traffic).
// Single delta vs R5: slotted accumulators (16 slots/quantity) + shfl-tree
// k3_out, removing the same-address atomic serialization tail in k2.

constexpr int B = 4, N = 512, M = 512, D = 128;
constexpr int TN = 64, TM = 64;
constexpr int LSTR = D + 4;           // +4 floats pad: rows shift 4 banks -> <=2-way conflicts
constexpr int NSLOT = 16;             // accumulator slots per quantity
#define SENT -3.0e38f                  // "minus infinity" that is exp-safe (no inf-inf NaN)

// lengths: jnp.int64 in the reference, but JAX w/o x64 gives int32. Lengths are
// >=64, so odd int32 slots are 0 iff the buffer is int64 little-endian.
__device__ __forceinline__ int load_len(const int* p, int b) {
  bool is64 = (p[1] == 0) && (p[3] == 0);
  return is64 ? p[2 * b] : p[b];
}

// Stage x/y 64x128 tiles into LDS; compute zr[4][4] for
// n = n0+ty+16i, m = m0+tx+16j (strided micro-tile; <=2-way LDS conflicts).
__device__ __forceinline__ void compute_tile(const float* __restrict__ x,
                                             const float* __restrict__ y,
                                             int b, int n0, int m0, int tid,
                                             float* xs, float* ys,
                                             float zr[4][4]) {
  const float4* xg = (const float4*)(x + (size_t)(b * N + n0) * D);
  const float4* yg = (const float4*)(y + (size_t)(b * M + m0) * D);
#pragma unroll
  for (int k = 0; k < 8; ++k) {
    int idx = tid + k * 256;     // float4 index within 64x128 tile (2048 total)
    int r = idx >> 5;            // 32 float4 per row
    int c = (idx & 31) << 2;
    *(float4*)&xs[r * LSTR + c] = xg[idx];
    *(float4*)&ys[r * LSTR + c] = yg[idx];
  }
  __syncthreads();

  const int tx = tid & 15;
  const int ty = tid >> 4;
#pragma unroll
  for (int i = 0; i < 4; ++i)
#pragma unroll
    for (int j = 0; j < 4; ++j) zr[i][j] = 0.f;

#pragma unroll 4
  for (int dd = 0; dd < D; dd += 4) {
    float4 xa[4], yb[4];
#pragma unroll
    for (int i = 0; i < 4; ++i) xa[i] = *(const float4*)&xs[(ty + 16 * i) * LSTR + dd];
#pragma unroll
    for (int j = 0; j < 4; ++j) yb[j] = *(const float4*)&ys[(tx + 16 * j) * LSTR + dd];
#pragma unroll
    for (int i = 0; i < 4; ++i)
#pragma unroll
      for (int j = 0; j < 4; ++j) {
        zr[i][j] += fabsf(xa[i].x - yb[j].x);
        zr[i][j] += fabsf(xa[i].y - yb[j].y);
        zr[i][j] += fabsf(xa[i].z - yb[j].z);
        zr[i][j] += fabsf(xa[i].w - yb[j].w);
      }
  }
}

// k1: per-tile softmax partials only.
//   rp[b][mt][n] = (max, sumexp) over this m-tile's valid m, for row n
//   cp[b][nt][m] = (max, sumexp) over this n-tile's valid n, for col m
__global__ __launch_bounds__(256) void k1_stats(const float* __restrict__ x,
                                                const float* __restrict__ y,
                                                const int* __restrict__ xlen,
                                                const int* __restrict__ ylen,
                                                float2* __restrict__ rp,
                                                float2* __restrict__ cp,
                                                float* __restrict__ acc) {
  __shared__ float xs[TN * LSTR];
  __shared__ float ys[TM * LSTR];
  __shared__ float2 colp[4][TM];
  const int b  = blockIdx.z;
  const int n0 = blockIdx.y * TN;
  const int m0 = blockIdx.x * TM;
  const int tid = threadIdx.x;
  const int xl = load_len(xlen, b);
  const int yl = load_len(ylen, b);

  if (blockIdx.x == 0 && blockIdx.y == 0 && blockIdx.z == 0 && tid < 2 * B * NSLOT)
    acc[tid] = 0.f;   // visible to k2's atomics after kernel boundary

  float zr[4][4];
  compute_tile(x, y, b, n0, m0, tid, xs, ys, zr);

  const int tx = tid & 15;
  const int ty = tid >> 4;
  const int wv = tid >> 6;

  // row partials: reduce over the 16 tx lanes (lane bits 0..3)
#pragma unroll
  for (int i = 0; i < 4; ++i) {
    float lm = SENT;
#pragma unroll
    for (int j = 0; j < 4; ++j)
      if (m0 + tx + 16 * j < yl) lm = fmaxf(lm, -zr[i][j]);
#pragma unroll
    for (int off = 1; off <= 8; off <<= 1) lm = fmaxf(lm, __shfl_xor(lm, off, 64));
    float ls = 0.f;
#pragma unroll
    for (int j = 0; j < 4; ++j)
      if (m0 + tx + 16 * j < yl) ls += __expf(-zr[i][j] - lm);
#pragma unroll
    for (int off = 1; off <= 8; off <<= 1) ls += __shfl_xor(ls, off, 64);
    if (tx == 0)
      rp[((b * 8 + (m0 >> 6)) * N) + n0 + ty + 16 * i] = make_float2(lm, ls);
  }

  // col partials: reduce ty within wave (lane bits 4..5), then 4 waves via LDS
#pragma unroll
  for (int j = 0; j < 4; ++j) {
    float cm = SENT;
#pragma unroll
    for (int i = 0; i < 4; ++i)
      if (n0 + ty + 16 * i < xl) cm = fmaxf(cm, -zr[i][j]);
    cm = fmaxf(cm, __shfl_xor(cm, 16, 64));
    cm = fmaxf(cm, __shfl_xor(cm, 32, 64));
    float cs = 0.f;
#pragma unroll
    for (int i = 0; i < 4; ++i)
      if (n0 + ty + 16 * i < xl) cs += __expf(-zr[i][j] - cm);
    cs += __shfl_xor(cs, 16, 64);
    cs += __shfl_xor(cs, 32, 64);
    if ((ty & 3) == 0) colp[wv][tx + 16 * j] = make_float2(cm, cs);
  }
  __syncthreads();
  if (tid < TM) {
    float2 p0 = colp[0][tid], p1 = colp[1][tid], p2 = colp[2][tid], p3 = colp[3][tid];
    float gm = fmaxf(fmaxf(p0.x, p1.x), fmaxf(p2.x, p3.x));
    float gs = p0.y * __expf(p0.x - gm) + p1.y * __expf(p1.x - gm) +
               p2.y * __expf(p2.x - gm) + p3.y * __expf(p3.x - gm);
    cp[((b * 8 + (n0 >> 6)) * M) + m0 + tid] = make_float2(gm, gs);
  }
}

// k2: recompute zr, merge this block's row/col stats, accumulate num/den into
// slotted accumulators. No fence, no counter.
__global__ __launch_bounds__(256) void k2_final(const float* __restrict__ x,
                                                const float* __restrict__ y,
                                                const int* __restrict__ xlen,
                                                const int* __restrict__ ylen,
                                                const float2* __restrict__ rp,
                                                const float2* __restrict__ cp,
                                                float* __restrict__ acc) {
  __shared__ float xs[TN * LSTR];
  __shared__ float ys[TM * LSTR];
  __shared__ float rm_s[TN], ri_s[TN], cm_s[TM], ci_s[TM];
  __shared__ float red[4][2];
  const int b  = blockIdx.z;
  const int n0 = blockIdx.y * TN;
  const int m0 = blockIdx.x * TM;
  const int tid = threadIdx.x;
  const int xl = load_len(xlen, b);
  const int yl = load_len(ylen, b);

  // merge the 8 per-tile partials for this block's rows (tid<64) / cols
  // (64<=tid<128); online-softmax rescale, masked partials contribute 0.
  if (tid < 128) {
    bool isrow = tid < 64;
    int p = isrow ? (n0 + tid) : (m0 + tid - 64);
    const float2* src = isrow ? rp : cp;
    float2 v[8];
    float gm = SENT;
#pragma unroll
    for (int t = 0; t < 8; ++t) {
      v[t] = src[(b * 8 + t) * 512 + p];
      gm = fmaxf(gm, v[t].x);
    }
    float gs = 0.f;
#pragma unroll
    for (int t = 0; t < 8; ++t) gs += v[t].y * __expf(v[t].x - gm);
    float inv = 1.0f / gs;            // inf only for fully-masked rows/cols (unused)
    if (isrow) { rm_s[tid] = gm; ri_s[tid] = inv; }
    else       { cm_s[tid - 64] = gm; ci_s[tid - 64] = inv; }
  }
  // compute_tile's __syncthreads() publishes the stat merge too

  float zr[4][4];
  compute_tile(x, y, b, n0, m0, tid, xs, ys, zr);

  const int tx = tid & 15;
  const int ty = tid >> 4;
  float num = 0.f, den = 0.f;
#pragma unroll
  for (int i = 0; i < 4; ++i) {
    int nl = ty + 16 * i;
    if (n0 + nl >= xl) continue;
    float rm = rm_s[nl], ri = ri_s[nl];
#pragma unroll
    for (int j = 0; j < 4; ++j) {
      int ml = tx + 16 * j;
      if (m0 + ml >= yl) continue;
      float zv = zr[i][j];
      float w = -zv;
      float alpha = __expf(w - cm_s[ml]) * ci_s[ml];
      float beta  = __expf(w - rm) * ri;
      float a = alpha + beta - alpha * beta;
      num += a * zv;
      den += a;
    }
  }
#pragma unroll
  for (int off = 32; off > 0; off >>= 1) {
    num += __shfl_xor(num, off, 64);
    den += __shfl_xor(den, off, 64);
  }
  __syncthreads();                      // xs/ys & stat LDS done; reuse red
  if ((tid & 63) == 0) { red[tid >> 6][0] = num; red[tid >> 6][1] = den; }
  __syncthreads();
  if (tid == 0) {
    int slot = (blockIdx.x + blockIdx.y) & (NSLOT - 1);
    atomicAdd(&acc[b * NSLOT + slot],
              red[0][0] + red[1][0] + red[2][0] + red[3][0]);
    atomicAdd(&acc[(B + b) * NSLOT + slot],
              red[0][1] + red[1][1] + red[2][1] + red[3][1]);
  }
}

// One wave. acc layout: quantity q (0..3 = num[b], 4..7 = den[b]) x 16 slots.
// Lane l holds acc[l] (q = l>>4) and acc[64+l] (q = 4 + (l>>4)); shfl-xor over
// the 16-lane group reduces both; group-leader lane b*16 writes out[b].
__global__ void k3_out(const float* __restrict__ acc, float* __restrict__ out) {
  int l = threadIdx.x;
  float a = acc[l];
  float d = acc[64 + l];
#pragma unroll
  for (int off = 1; off <= 8; off <<= 1) {
    a += __shfl_xor(a, off, 64);
    d += __shfl_xor(d, off, 64);
  }
  if ((l & 15) == 0) out[l >> 4] = -a / d;
}

extern "C" void kernel_launch(void* const* d_in, const int* in_sizes, int n_in,
                              void* d_out, int out_size, void* d_ws, size_t ws_size,
                              hipStream_t stream) {
  const float* x    = (const float*)d_in[0];
  const float* y    = (const float*)d_in[1];
  const int*   xlen = (const int*)d_in[2];
  const int*   ylen = (const int*)d_in[3];
  float* out = (float*)d_out;

  float* ws = (float*)d_ws;
  float2* rp  = (float2*)ws;              size_t off = (size_t)B * 8 * N * 2;  // 128 KB
  float2* cp  = (float2*)(ws + off);      off += (size_t)B * 8 * M * 2;        // 128 KB
  float*  acc = ws + off;                 off += 2 * B * NSLOT;

  k1_stats<<<dim3(M / TM, N / TN, B), 256, 0, stream>>>(x, y, xlen, ylen, rp, cp, acc);
  k2_final<<<dim3(M / TM, N / TN, B), 256, 0, stream>>>(x, y, xlen, ylen, rp, cp, acc);
  k3_out<<<1, 64, 0, stream>>>(acc, out);
}